// Round 5
// baseline (213.300 us; speedup 1.0000x reference)
//
#include <hip/hip_runtime.h>
#include <hip/hip_bf16.h>

typedef __attribute__((ext_vector_type(8))) short short8;
typedef __attribute__((ext_vector_type(4))) float f32x4;
typedef __attribute__((ext_vector_type(4))) unsigned short u16x4;

#define MFMA16(a,b,c) __builtin_amdgcn_mfma_f32_16x16x32_bf16((a),(b),(c),0,0,0)

__device__ __forceinline__ ushort f2bf(float x) {
  union { float f; unsigned u; } v; v.f = x;
  unsigned u = v.u;
  u = (u + 0x7fffu + ((u >> 16) & 1u)) >> 16;
  return (ushort)u;
}

__device__ __forceinline__ float bf2f(ushort u) {
  union { unsigned u; float f; } v; v.u = ((unsigned)u) << 16;
  return v.f;
}

__device__ __forceinline__ short8 ld8(const ushort* p) {
  return *reinterpret_cast<const short8*>(p);
}

__device__ __forceinline__ f32x4 ldnt4(const float* p) {
  return __builtin_nontemporal_load(reinterpret_cast<const f32x4*>(p));
}

__device__ __forceinline__ void stnt4(float* p, f32x4 v) {
  __builtin_nontemporal_store(v, reinterpret_cast<f32x4*>(p));
}

// ---- kernel 0: fp32 -> bf16 conversion (vectorized float4 -> ushort4) ----
__global__ void conv_kernel(const float* __restrict__ value,
                            const float* __restrict__ w_in,
                            const float* __restrict__ w_out,
                            ushort* __restrict__ vbf,
                            ushort* __restrict__ wbf,
                            ushort* __restrict__ owbf) {
  int i = blockIdx.x * 256 + threadIdx.x;   // float4 index
  const float* src; ushort* dst; int j;
  if (i < 524288)      { src = value; dst = vbf;  j = i; }
  else if (i < 573440) { src = w_in;  dst = wbf;  j = i - 524288; }
  else                 { src = w_out; dst = owbf; j = i - 573440; }
  float4 v = reinterpret_cast<const float4*>(src)[j];
  u16x4 o;
  o[0] = f2bf(v.x); o[1] = f2bf(v.y); o[2] = f2bf(v.z); o[3] = f2bf(v.w);
  reinterpret_cast<u16x4*>(dst)[j] = o;
}

// ---- kernel 1: qkv projection GEMM (8192x256)@(256x768)^T, scatter to head layouts ----
__global__ __launch_bounds__(256) void qkv_kernel(
    const ushort* __restrict__ vbf, const ushort* __restrict__ wbf,
    const float* __restrict__ bias,
    ushort* __restrict__ qh, ushort* __restrict__ kh, ushort* __restrict__ vv) {
  int tid = threadIdx.x;
  int wave = tid >> 6, lane = tid & 63;
  int lq = lane & 15, lg = lane >> 4;
  int r0 = blockIdx.x * 16;
  int c0 = (blockIdx.y * 4 + wave) * 16;
  f32x4 acc = {0.f, 0.f, 0.f, 0.f};
  const ushort* ap = vbf + (size_t)(r0 + lq) * 256 + lg * 8;
  const ushort* bp = wbf + (size_t)(c0 + lq) * 256 + lg * 8;
#pragma unroll
  for (int k0 = 0; k0 < 256; k0 += 32)
    acc = MFMA16(ld8(ap + k0), ld8(bp + k0), acc);
  int c = c0 + lq;
  float bv = bias[c];
#pragma unroll
  for (int r = 0; r < 4; ++r) {
    int row = r0 + lg * 4 + r;       // row = n*8 + b
    int n = row >> 3, b = row & 7;
    float v = acc[r] + bv;
    if (c < 256) {
      int h = c >> 5, d = c & 31;
      qh[((size_t)(b * 8 + h) * 1024 + n) * 32 + d] = f2bf(v * 0.17677669529663689f);
    } else if (c < 512) {
      int cc = c - 256, h = cc >> 5, d = cc & 31;
      kh[((size_t)(b * 8 + h) * 1024 + n) * 32 + d] = f2bf(v);
    } else {
      int cc = c - 512, h = cc >> 5, d = cc & 31;
      vv[((size_t)(b * 8 + h) * 1024 + n) * 32 + d] = f2bf(v);
    }
  }
}

// ---- kernel 1b: transpose vv[bh][m][d] -> vt[bh][d][m], coalesced both sides ----
__global__ __launch_bounds__(256) void vtrans_kernel(const ushort* __restrict__ vv,
                                                     ushort* __restrict__ vt) {
  __shared__ ushort t[32][73];   // pad 73: <=2-way bank aliasing both phases
  int tid = threadIdx.x;
  int bh = blockIdx.y, m0 = blockIdx.x * 64;
  int mm = tid >> 2, d0 = (tid & 3) * 8;
  short8 v = ld8(vv + ((size_t)bh * 1024 + m0 + mm) * 32 + d0);
#pragma unroll
  for (int j = 0; j < 8; ++j) t[d0 + j][mm] = (ushort)v[j];
  __syncthreads();
  int d = tid >> 3, mg = (tid & 7) * 8;
  short8 o;
#pragma unroll
  for (int j = 0; j < 8; ++j) o[j] = (short)t[d][mg + j];
  *reinterpret_cast<short8*>(vt + ((size_t)bh * 32 + d) * 1024 + m0 + mg) = o;
}

// ---- kernel 2: fused attention. 512 threads = 8 waves; wave owns m-chunk [w*128, w*128+128).
// Pipelined pos stream (pA/pB half-tiles, depth-1 cross-head prefetch), deferred
// normalization, ONE barrier per head with double-buffered pvred/rowsumT.
__global__ __launch_bounds__(512, 4) void attn_kernel(
    const ushort* __restrict__ qh, const ushort* __restrict__ kh,
    const ushort* __restrict__ vt, const float* __restrict__ pos,
    ushort* __restrict__ ao, float* __restrict__ avg_out) {
  __shared__ __align__(16) ushort attn_lds[16][1028];  // wave-private column slices
  __shared__ __align__(16) float pvred[2][8][16][32];  // double-buffered PV partials
  __shared__ __align__(16) float rowsumT[2][16][8];    // double-buffered rowsums

  int tid = threadIdx.x;
  int wave = tid >> 6, lane = tid & 63;
  int lq = lane & 15, lg = lane >> 4;
  int n0 = blockIdx.x * 16;
  int b = blockIdx.y;
  int mb = wave * 128;

  float avg[8][4];
#pragma unroll
  for (int t = 0; t < 8; ++t)
#pragma unroll
    for (int r = 0; r < 4; ++r) avg[t][r] = 0.f;

  // pos row base for this thread (head h adds h<<20, row r adds r*1024)
  const float* prow0 = pos + ((size_t)(b * 8) << 20) + (size_t)(n0 + lg * 4) * 1024 + mb + lq * 8;

  // prologue: prefetch phase-A pos for head 0
  f32x4 pA[4];
#pragma unroll
  for (int r = 0; r < 4; ++r) pA[r] = ldnt4(prow0 + (size_t)r * 1024);

  int buf = 0;
  for (int h = 0; h < 8; ++h) {
    int bh = b * 8 + h;
    const float* prow = prow0 + ((size_t)h << 20);
    const ushort* kp = kh + (size_t)bh * 32768 + lg * 8;

    // issue qa + phase-A K loads, THEN pB (stays outstanding through phase A)
    short8 qa = ld8(qh + ((size_t)bh * 1024 + n0 + lq) * 32 + lg * 8);
    short8 ka0 = ld8(kp + (size_t)(mb + lq * 8 + 0) * 32);
    short8 ka1 = ld8(kp + (size_t)(mb + lq * 8 + 1) * 32);
    short8 ka2 = ld8(kp + (size_t)(mb + lq * 8 + 2) * 32);
    short8 ka3 = ld8(kp + (size_t)(mb + lq * 8 + 3) * 32);
    f32x4 pB[4];
#pragma unroll
    for (int r = 0; r < 4; ++r) pB[r] = ldnt4(prow + (size_t)r * 1024 + 4);

    float rs[4] = {0.f, 0.f, 0.f, 0.f};
    short8 wreg[4];

    // ---- phase A: tiles t=0..3 (m = mb + lq*8 + t), gate with pA ----
    {
      f32x4 z = {0.f, 0.f, 0.f, 0.f};
      f32x4 S0 = MFMA16(qa, ka0, z);
      f32x4 S1 = MFMA16(qa, ka1, z);
      f32x4 S2 = MFMA16(qa, ka2, z);
      f32x4 S3 = MFMA16(qa, ka3, z);
      f32x4 S[4] = {S0, S1, S2, S3};
#pragma unroll
      for (int r = 0; r < 4; ++r) {
#pragma unroll
        for (int t = 0; t < 4; ++t) {
          float p = fminf(10.f, fmaxf(-10.f, pA[r][t]));
          float c = fminf(10.f, fmaxf(-10.f, S[t][r]));
          float w = __expf(c - 10.f) * __builtin_amdgcn_rcpf(1.f + __expf(-p));
          rs[r] += w;
          wreg[r][t] = (short)f2bf(w);
        }
      }
    }
    // ---- phase B: tiles t=4..7, gate with pB ----
    {
      short8 kb0 = ld8(kp + (size_t)(mb + lq * 8 + 4) * 32);
      short8 kb1 = ld8(kp + (size_t)(mb + lq * 8 + 5) * 32);
      short8 kb2 = ld8(kp + (size_t)(mb + lq * 8 + 6) * 32);
      short8 kb3 = ld8(kp + (size_t)(mb + lq * 8 + 7) * 32);
      f32x4 z = {0.f, 0.f, 0.f, 0.f};
      f32x4 S0 = MFMA16(qa, kb0, z);
      f32x4 S1 = MFMA16(qa, kb1, z);
      f32x4 S2 = MFMA16(qa, kb2, z);
      f32x4 S3 = MFMA16(qa, kb3, z);
      f32x4 S[4] = {S0, S1, S2, S3};
#pragma unroll
      for (int r = 0; r < 4; ++r) {
#pragma unroll
        for (int t = 0; t < 4; ++t) {
          float p = fminf(10.f, fmaxf(-10.f, pB[r][t]));
          float c = fminf(10.f, fmaxf(-10.f, S[t][r]));
          float w = __expf(c - 10.f) * __builtin_amdgcn_rcpf(1.f + __expf(-p));
          rs[r] += w;
          wreg[r][4 + t] = (short)f2bf(w);
        }
      }
    }
    // ---- stage unnormalized w to LDS (wave-private, XOR swizzle) ----
#pragma unroll
    for (int r = 0; r < 4; ++r) {
      int row = lg * 4 + r;
      int col = (mb + lq * 8) ^ ((row & 7) << 3);
      *reinterpret_cast<short8*>(&attn_lds[row][col]) = wreg[r];
    }
    // ---- rowsum partials -> LDS ----
#pragma unroll
    for (int r = 0; r < 4; ++r) {
      rs[r] += __shfl_xor(rs[r], 1);
      rs[r] += __shfl_xor(rs[r], 2);
      rs[r] += __shfl_xor(rs[r], 4);
      rs[r] += __shfl_xor(rs[r], 8);
    }
    if (lq == 0) {
#pragma unroll
      for (int r = 0; r < 4; ++r) rowsumT[buf][lg * 4 + r][wave] = rs[r];
    }
    // ---- PV on unnormalized w (wave-private LDS region; no barrier needed) ----
    f32x4 acc0 = {0.f, 0.f, 0.f, 0.f}, acc1 = {0.f, 0.f, 0.f, 0.f};
    const ushort* vp = vt + (size_t)bh * 32768 + mb + lg * 8;
#pragma unroll
    for (int ks = 0; ks < 4; ++ks) {
      int col = (mb + ks * 32 + lg * 8) ^ ((lq & 7) << 3);
      short8 pa = *reinterpret_cast<const short8*>(&attn_lds[lq][col]);
      acc0 = MFMA16(pa, ld8(vp + (size_t)lq * 1024 + ks * 32), acc0);
      acc1 = MFMA16(pa, ld8(vp + (size_t)(lq + 16) * 1024 + ks * 32), acc1);
    }
    // ---- prefetch next head's phase-A pos: issued LAST -> stays in flight
    //      across pvred write + barrier + epilogue ----
    if (h < 7) {
      const float* pn = prow + (1u << 20);
#pragma unroll
      for (int r = 0; r < 4; ++r) pA[r] = ldnt4(pn + (size_t)r * 1024);
    }
    // ---- unnormalized PV partials -> LDS ----
#pragma unroll
    for (int r = 0; r < 4; ++r) {
      pvred[buf][wave][lg * 4 + r][lq] = acc0[r];
      pvred[buf][wave][lg * 4 + r][lq + 16] = acc1[r];
    }
    __syncthreads();                       // the ONLY barrier per head
    // ---- epilogue: inv from rowsums, avg += w*inv, reduce pvred*inv -> ao ----
    {
#pragma unroll
      for (int r = 0; r < 4; ++r) {
        int row = lg * 4 + r;
        float4 a0 = *reinterpret_cast<const float4*>(&rowsumT[buf][row][0]);
        float4 a1 = *reinterpret_cast<const float4*>(&rowsumT[buf][row][4]);
        float invr = __builtin_amdgcn_rcpf(a0.x + a0.y + a0.z + a0.w +
                                           a1.x + a1.y + a1.z + a1.w);
#pragma unroll
        for (int t = 0; t < 8; ++t)
          avg[t][r] += bf2f((ushort)wreg[r][t]) * invr;
      }
      int n = tid >> 5, d = tid & 31;
      float4 a0 = *reinterpret_cast<const float4*>(&rowsumT[buf][n][0]);
      float4 a1 = *reinterpret_cast<const float4*>(&rowsumT[buf][n][4]);
      float invn = __builtin_amdgcn_rcpf(a0.x + a0.y + a0.z + a0.w +
                                         a1.x + a1.y + a1.z + a1.w);
      float s = 0.f;
#pragma unroll
      for (int w = 0; w < 8; ++w) s += pvred[buf][w][n][d];
      ao[((size_t)(n0 + n) * 8 + b) * 256 + h * 32 + d] = f2bf(s * invn);
    }
    buf ^= 1;
  }
  // ---- write averaged attention (mean over 8 heads), nontemporal float4 ----
#pragma unroll
  for (int r = 0; r < 4; ++r) {
    int n = n0 + lg * 4 + r;
    float* op = avg_out + (size_t)b * 1048576 + (size_t)n * 1024 + mb + lq * 8;
    f32x4 v0 = {avg[0][r] * 0.125f, avg[1][r] * 0.125f, avg[2][r] * 0.125f, avg[3][r] * 0.125f};
    f32x4 v1 = {avg[4][r] * 0.125f, avg[5][r] * 0.125f, avg[6][r] * 0.125f, avg[7][r] * 0.125f};
    stnt4(op, v0);
    stnt4(op + 4, v1);
  }
}

// ---- kernel 3: output projection (8192x256)@(256x256)^T + bias -> d_out (fp32) ----
__global__ __launch_bounds__(256) void oproj_kernel(
    const ushort* __restrict__ ao, const ushort* __restrict__ owbf,
    const float* __restrict__ ob, float* __restrict__ outp) {
  int tid = threadIdx.x;
  int wave = tid >> 6, lane = tid & 63;
  int lq = lane & 15, lg = lane >> 4;
  int r0 = blockIdx.x * 16;
  int c0 = (blockIdx.y * 4 + wave) * 16;
  f32x4 acc = {0.f, 0.f, 0.f, 0.f};
  const ushort* ap = ao + (size_t)(r0 + lq) * 256 + lg * 8;
  const ushort* bp = owbf + (size_t)(c0 + lq) * 256 + lg * 8;
#pragma unroll
  for (int k0 = 0; k0 < 256; k0 += 32)
    acc = MFMA16(ld8(ap + k0), ld8(bp + k0), acc);
  int c = c0 + lq;
  float bv = ob[c];
#pragma unroll
  for (int r = 0; r < 4; ++r) {
    int row = r0 + lg * 4 + r;
    outp[(size_t)row * 256 + c] = acc[r] + bv;
  }
}

extern "C" void kernel_launch(void* const* d_in, const int* in_sizes, int n_in,
                              void* d_out, int out_size, void* d_ws, size_t ws_size,
                              hipStream_t stream) {
  const float* value = (const float*)d_in[0];
  const float* pos   = (const float*)d_in[1];
  const float* w_in  = (const float*)d_in[2];
  const float* b_in  = (const float*)d_in[3];
  const float* w_out = (const float*)d_in[4];
  const float* b_out = (const float*)d_in[5];

  char* ws = (char*)d_ws;
  ushort* vbf  = (ushort*)(ws);                 // 8192x256 bf16 (4 MB); reused as vt after qkv
  ushort* wbf  = (ushort*)(ws + 4194304);       // 768x256 bf16
  ushort* owbf = (ushort*)(ws + 4587520);       // 256x256 bf16
  ushort* qh   = (ushort*)(ws + 4718592);       // 64x1024x32 bf16 (4 MB)
  ushort* kh   = (ushort*)(ws + 8912896);       // 64x1024x32 bf16 (4 MB)
  ushort* vv   = (ushort*)(ws + 13107200);      // 64x1024x32 bf16 (4 MB, row-major V)
  ushort* vt   = (ushort*)(ws);                 // 64x32x1024 bf16 (4 MB, overlays dead vbf)
  ushort* ao   = (ushort*)(ws + 17301504);      // 8192x256 bf16 (4 MB)

  float* outp = (float*)d_out;                  // (N,B,E) fp32
  float* avgp = outp + 2097152;                 // (B,N,N) fp32

  conv_kernel<<<2304, 256, 0, stream>>>(value, w_in, w_out, vbf, wbf, owbf);
  qkv_kernel<<<dim3(512, 12), 256, 0, stream>>>(vbf, wbf, b_in, qh, kh, vv);
  vtrans_kernel<<<dim3(16, 64), 256, 0, stream>>>(vv, vt);
  attn_kernel<<<dim3(64, 8), 512, 0, stream>>>(qh, kh, vt, pos, ao, avgp);
  oproj_kernel<<<dim3(512, 4), 256, 0, stream>>>(ao, owbf, b_out, outp);
}

// Round 6
// 178.819 us; speedup vs baseline: 1.1928x; 1.1928x over previous
//
#include <hip/hip_runtime.h>
#include <hip/hip_bf16.h>

typedef __attribute__((ext_vector_type(8))) short short8;
typedef __attribute__((ext_vector_type(4))) float f32x4;
typedef __attribute__((ext_vector_type(4))) unsigned short u16x4;

#define MFMA16(a,b,c) __builtin_amdgcn_mfma_f32_16x16x32_bf16((a),(b),(c),0,0,0)

__device__ __forceinline__ ushort f2bf(float x) {
  union { float f; unsigned u; } v; v.f = x;
  unsigned u = v.u;
  u = (u + 0x7fffu + ((u >> 16) & 1u)) >> 16;
  return (ushort)u;
}

__device__ __forceinline__ float bf2f(ushort u) {
  union { unsigned u; float f; } v; v.u = ((unsigned)u) << 16;
  return v.f;
}

__device__ __forceinline__ short8 ld8(const ushort* p) {
  return *reinterpret_cast<const short8*>(p);
}

// async global->LDS DMA: 64 lanes x 16B = 1KB per instruction, VGPR-free.
__device__ __forceinline__ void glds16(const float* g, float* l) {
  __builtin_amdgcn_global_load_lds(
      (const __attribute__((address_space(1))) unsigned int*)g,
      (__attribute__((address_space(3))) unsigned int*)(void*)l, 16, 0, 0);
}

// ---- kernel 0: fp32 -> bf16 conversion (vectorized float4 -> ushort4) ----
__global__ void conv_kernel(const float* __restrict__ value,
                            const float* __restrict__ w_in,
                            const float* __restrict__ w_out,
                            ushort* __restrict__ vbf,
                            ushort* __restrict__ wbf,
                            ushort* __restrict__ owbf) {
  int i = blockIdx.x * 256 + threadIdx.x;   // float4 index
  const float* src; ushort* dst; int j;
  if (i < 524288)      { src = value; dst = vbf;  j = i; }
  else if (i < 573440) { src = w_in;  dst = wbf;  j = i - 524288; }
  else                 { src = w_out; dst = owbf; j = i - 573440; }
  float4 v = reinterpret_cast<const float4*>(src)[j];
  u16x4 o;
  o[0] = f2bf(v.x); o[1] = f2bf(v.y); o[2] = f2bf(v.z); o[3] = f2bf(v.w);
  reinterpret_cast<u16x4*>(dst)[j] = o;
}

// ---- kernel 1: qkv projection GEMM (8192x256)@(256x768)^T, scatter to head layouts ----
__global__ __launch_bounds__(256) void qkv_kernel(
    const ushort* __restrict__ vbf, const ushort* __restrict__ wbf,
    const float* __restrict__ bias,
    ushort* __restrict__ qh, ushort* __restrict__ kh, ushort* __restrict__ vv) {
  int tid = threadIdx.x;
  int wave = tid >> 6, lane = tid & 63;
  int lq = lane & 15, lg = lane >> 4;
  int r0 = blockIdx.x * 16;
  int c0 = (blockIdx.y * 4 + wave) * 16;
  f32x4 acc = {0.f, 0.f, 0.f, 0.f};
  const ushort* ap = vbf + (size_t)(r0 + lq) * 256 + lg * 8;
  const ushort* bp = wbf + (size_t)(c0 + lq) * 256 + lg * 8;
#pragma unroll
  for (int k0 = 0; k0 < 256; k0 += 32)
    acc = MFMA16(ld8(ap + k0), ld8(bp + k0), acc);
  int c = c0 + lq;
  float bv = bias[c];
#pragma unroll
  for (int r = 0; r < 4; ++r) {
    int row = r0 + lg * 4 + r;       // row = n*8 + b
    int n = row >> 3, b = row & 7;
    float v = acc[r] + bv;
    if (c < 256) {
      int h = c >> 5, d = c & 31;
      qh[((size_t)(b * 8 + h) * 1024 + n) * 32 + d] = f2bf(v * 0.17677669529663689f);
    } else if (c < 512) {
      int cc = c - 256, h = cc >> 5, d = cc & 31;
      kh[((size_t)(b * 8 + h) * 1024 + n) * 32 + d] = f2bf(v);
    } else {
      int cc = c - 512, h = cc >> 5, d = cc & 31;
      vv[((size_t)(b * 8 + h) * 1024 + n) * 32 + d] = f2bf(v);
    }
  }
}

// ---- kernel 1b: transpose vv[bh][m][d] -> vt[bh][d][m], coalesced both sides ----
__global__ __launch_bounds__(256) void vtrans_kernel(const ushort* __restrict__ vv,
                                                     ushort* __restrict__ vt) {
  __shared__ ushort t[32][73];
  int tid = threadIdx.x;
  int bh = blockIdx.y, m0 = blockIdx.x * 64;
  int mm = tid >> 2, d0 = (tid & 3) * 8;
  short8 v = ld8(vv + ((size_t)bh * 1024 + m0 + mm) * 32 + d0);
#pragma unroll
  for (int j = 0; j < 8; ++j) t[d0 + j][mm] = (ushort)v[j];
  __syncthreads();
  int d = tid >> 3, mg = (tid & 7) * 8;
  short8 o;
#pragma unroll
  for (int j = 0; j < 8; ++j) o[j] = (short)t[d][mg + j];
  *reinterpret_cast<short8*>(vt + ((size_t)bh * 32 + d) * 1024 + m0 + mg) = o;
}

// ---- kernel 2: fused attention, pos streamed via global_load_lds DMA pipeline.
// 512 threads = 8 waves. Per half-step (16/block): all waves consume one staged
// [16][512] fp32 pos buffer; wave w owns cols [w*64, w*64+64), m = hf*512+w*64+lq*4+t.
__global__ __launch_bounds__(512, 2) void attn_kernel(
    const ushort* __restrict__ qh, const ushort* __restrict__ kh,
    const ushort* __restrict__ vt, const float* __restrict__ pos,
    ushort* __restrict__ ao, float* __restrict__ avg_out) {
  __shared__ __align__(16) float pos_lds[2][16][516];   // 66 KB, double-buffered halves
  __shared__ __align__(16) ushort attn_lds[16][1032];   // 33 KB, unnormalized w (bf16)
  __shared__ __align__(16) float pvred[8][16][32];      // 16 KB
  __shared__ float rowsumT[16][8];

  int tid = threadIdx.x;
  int wave = tid >> 6, lane = tid & 63;
  int lq = lane & 15, lg = lane >> 4;
  int n0 = blockIdx.x * 16;
  int b = blockIdx.y;

  // stage half-step s (head s>>1, half s&1) into buffer s&1: 4 DMA instrs/wave
  auto stage = [&](int s) {
    int buf = s & 1;
    const float* gb = pos + ((size_t)(b * 8 + (s >> 1)) << 20)
                          + (size_t)n0 * 1024 + (s & 1) * 512;
    int r = wave * 2;
    glds16(gb + (size_t)r * 1024 +       lane * 4, &pos_lds[buf][r][0]);
    glds16(gb + (size_t)r * 1024 + 256 + lane * 4, &pos_lds[buf][r][256]);
    glds16(gb + (size_t)(r + 1) * 1024 +       lane * 4, &pos_lds[buf][r + 1][0]);
    glds16(gb + (size_t)(r + 1) * 1024 + 256 + lane * 4, &pos_lds[buf][r + 1][256]);
  };

  float avg[8][4];
#pragma unroll
  for (int j = 0; j < 8; ++j)
#pragma unroll
    for (int r = 0; r < 4; ++r) avg[j][r] = 0.f;

  // prologue: fill both buffers
  stage(0);
  stage(1);
  __syncthreads();

  for (int h = 0; h < 8; ++h) {
    int bh = b * 8 + h;
    const ushort* kp = kh + (size_t)bh * 32768;
    const ushort* vp = vt + (size_t)bh * 32768;
    short8 qa = ld8(qh + ((size_t)bh * 1024 + n0 + lq) * 32 + lg * 8);
    f32x4 acc0 = {0.f, 0.f, 0.f, 0.f}, acc1 = {0.f, 0.f, 0.f, 0.f};
    float rs[4] = {0.f, 0.f, 0.f, 0.f};
    u16x4 wA[4], wB[4];

    // one half: QK^T(4 tiles) -> gate from LDS pos -> w to attn_lds -> PV partial
    auto half_body = [&](int hf, u16x4* wv) {
      int buf = (h * 2 + hf) & 1;
      int mwin = hf * 512 + wave * 64;
      int lcol = wave * 64 + lq * 4;
      f32x4 S[4];
#pragma unroll
      for (int t = 0; t < 4; ++t) {
        f32x4 z = {0.f, 0.f, 0.f, 0.f};
        S[t] = MFMA16(qa, ld8(kp + (size_t)(mwin + lq * 4 + t) * 32 + lg * 8), z);
      }
#pragma unroll
      for (int r = 0; r < 4; ++r) {
        int row = lg * 4 + r;
        f32x4 pv = *reinterpret_cast<const f32x4*>(&pos_lds[buf][row][lcol]);
#pragma unroll
        for (int t = 0; t < 4; ++t) {
          float p = fminf(10.f, fmaxf(-10.f, pv[t]));
          float c = fminf(10.f, fmaxf(-10.f, S[t][r]));
          float w = __expf(c - 10.f) * __builtin_amdgcn_rcpf(1.f + __expf(-p));
          rs[r] += w;
          wv[r][t] = f2bf(w);
        }
        int col = (mwin + lq * 4) ^ ((row & 7) << 3);
        *reinterpret_cast<u16x4*>(&attn_lds[row][col]) = wv[r];
      }
      // PV on this wave's own 64 columns (wave-private LDS region, no barrier)
#pragma unroll
      for (int ks = 0; ks < 2; ++ks) {
        int sb = mwin + ks * 32;
        int acol = (sb + lg * 8) ^ ((lq & 7) << 3);
        short8 pa = *reinterpret_cast<const short8*>(&attn_lds[lq][acol]);
        acc0 = MFMA16(pa, ld8(vp + (size_t)lq * 1024 + sb + lg * 8), acc0);
        acc1 = MFMA16(pa, ld8(vp + (size_t)(lq + 16) * 1024 + sb + lg * 8), acc1);
      }
    };

    // half A (s = 2h)
    half_body(0, wA);
    __syncthreads();                      // all waves done with buffer s; s+1 complete
    if (h * 2 + 2 < 16) stage(h * 2 + 2); // refill just-freed buffer
    // half B (s = 2h+1)
    half_body(1, wB);

    // rowsum reduce across the 16 lq lanes
#pragma unroll
    for (int r = 0; r < 4; ++r) {
      rs[r] += __shfl_xor(rs[r], 1);
      rs[r] += __shfl_xor(rs[r], 2);
      rs[r] += __shfl_xor(rs[r], 4);
      rs[r] += __shfl_xor(rs[r], 8);
    }
    if (lq == 0) {
#pragma unroll
      for (int r = 0; r < 4; ++r) rowsumT[lg * 4 + r][wave] = rs[r];
    }
#pragma unroll
    for (int r = 0; r < 4; ++r) {
      pvred[wave][lg * 4 + r][lq] = acc0[r];
      pvred[wave][lg * 4 + r][lq + 16] = acc1[r];
    }
    __syncthreads();                      // head barrier: pvred/rowsum visible; s+1 done
    if (h * 2 + 3 < 16) stage(h * 2 + 3);
    // epilogue: normalize, accumulate avg, reduce PV partials -> ao
#pragma unroll
    for (int r = 0; r < 4; ++r) {
      int row = lg * 4 + r;
      float4 a0 = *reinterpret_cast<const float4*>(&rowsumT[row][0]);
      float4 a1 = *reinterpret_cast<const float4*>(&rowsumT[row][4]);
      float invr = __builtin_amdgcn_rcpf(a0.x + a0.y + a0.z + a0.w +
                                         a1.x + a1.y + a1.z + a1.w);
#pragma unroll
      for (int j = 0; j < 4; ++j) avg[j][r] += bf2f(wA[r][j]) * invr;
#pragma unroll
      for (int j = 0; j < 4; ++j) avg[4 + j][r] += bf2f(wB[r][j]) * invr;
    }
    {
      int n = tid >> 5, d = tid & 31;
      float4 a0 = *reinterpret_cast<const float4*>(&rowsumT[n][0]);
      float4 a1 = *reinterpret_cast<const float4*>(&rowsumT[n][4]);
      float invn = __builtin_amdgcn_rcpf(a0.x + a0.y + a0.z + a0.w +
                                         a1.x + a1.y + a1.z + a1.w);
      float s = 0.f;
#pragma unroll
      for (int w = 0; w < 8; ++w) s += pvred[w][n][d];
      ao[((size_t)(n0 + n) * 8 + b) * 256 + h * 32 + d] = f2bf(s * invn);
    }
  }
  // ---- averaged attention output (mean over 8 heads), float4 nontemporal ----
#pragma unroll
  for (int r = 0; r < 4; ++r) {
    int n = n0 + lg * 4 + r;
    float* op = avg_out + (size_t)b * 1048576 + (size_t)n * 1024;
    f32x4 v0 = {avg[0][r] * 0.125f, avg[1][r] * 0.125f, avg[2][r] * 0.125f, avg[3][r] * 0.125f};
    f32x4 v1 = {avg[4][r] * 0.125f, avg[5][r] * 0.125f, avg[6][r] * 0.125f, avg[7][r] * 0.125f};
    __builtin_nontemporal_store(v0, reinterpret_cast<f32x4*>(op + wave * 64 + lq * 4));
    __builtin_nontemporal_store(v1, reinterpret_cast<f32x4*>(op + 512 + wave * 64 + lq * 4));
  }
}

// ---- kernel 3: output projection (8192x256)@(256x256)^T + bias -> d_out (fp32) ----
__global__ __launch_bounds__(256) void oproj_kernel(
    const ushort* __restrict__ ao, const ushort* __restrict__ owbf,
    const float* __restrict__ ob, float* __restrict__ outp) {
  int tid = threadIdx.x;
  int wave = tid >> 6, lane = tid & 63;
  int lq = lane & 15, lg = lane >> 4;
  int r0 = blockIdx.x * 16;
  int c0 = (blockIdx.y * 4 + wave) * 16;
  f32x4 acc = {0.f, 0.f, 0.f, 0.f};
  const ushort* ap = ao + (size_t)(r0 + lq) * 256 + lg * 8;
  const ushort* bp = owbf + (size_t)(c0 + lq) * 256 + lg * 8;
#pragma unroll
  for (int k0 = 0; k0 < 256; k0 += 32)
    acc = MFMA16(ld8(ap + k0), ld8(bp + k0), acc);
  int c = c0 + lq;
  float bv = ob[c];
#pragma unroll
  for (int r = 0; r < 4; ++r) {
    int row = r0 + lg * 4 + r;
    outp[(size_t)row * 256 + c] = acc[r] + bv;
  }
}

extern "C" void kernel_launch(void* const* d_in, const int* in_sizes, int n_in,
                              void* d_out, int out_size, void* d_ws, size_t ws_size,
                              hipStream_t stream) {
  const float* value = (const float*)d_in[0];
  const float* pos   = (const float*)d_in[1];
  const float* w_in  = (const float*)d_in[2];
  const float* b_in  = (const float*)d_in[3];
  const float* w_out = (const float*)d_in[4];
  const float* b_out = (const float*)d_in[5];

  char* ws = (char*)d_ws;
  ushort* vbf  = (ushort*)(ws);                 // 8192x256 bf16 (4 MB); reused as vt after qkv
  ushort* wbf  = (ushort*)(ws + 4194304);       // 768x256 bf16
  ushort* owbf = (ushort*)(ws + 4587520);       // 256x256 bf16
  ushort* qh   = (ushort*)(ws + 4718592);       // 64x1024x32 bf16 (4 MB)
  ushort* kh   = (ushort*)(ws + 8912896);       // 64x1024x32 bf16 (4 MB)
  ushort* vv   = (ushort*)(ws + 13107200);      // 64x1024x32 bf16 (4 MB, row-major V)
  ushort* vt   = (ushort*)(ws);                 // 64x32x1024 bf16 (4 MB, overlays dead vbf)
  ushort* ao   = (ushort*)(ws + 17301504);      // 8192x256 bf16 (4 MB)

  float* outp = (float*)d_out;                  // (N,B,E) fp32
  float* avgp = outp + 2097152;                 // (B,N,N) fp32

  conv_kernel<<<2304, 256, 0, stream>>>(value, w_in, w_out, vbf, wbf, owbf);
  qkv_kernel<<<dim3(512, 12), 256, 0, stream>>>(vbf, wbf, b_in, qh, kh, vv);
  vtrans_kernel<<<dim3(16, 64), 256, 0, stream>>>(vv, vt);
  attn_kernel<<<dim3(64, 8), 512, 0, stream>>>(qh, kh, vt, pos, ao, avgp);
  oproj_kernel<<<dim3(512, 4), 256, 0, stream>>>(ao, owbf, b_out, outp);
}